// Round 6
// baseline (201.833 us; speedup 1.0000x reference)
//
#include <hip/hip_runtime.h>

// ITA integer softmax — register-resident; nontemporal LOADS, plain STORES.
// x: (2,16,2048,2048) int32 -> out uint8 values stored as int32.
// EPS_MAX = 1.0 exactly, so every float-round shift == integer difference.
// Exact reformulation per row (K=2048, 128 groups of 16):
//   P_g = prefix-max of group maxima (init -128), d_g = P_g - P_{g-1}
//   s_g = sum_k 256 >> min(P_g - x_k, 31)
//   eps = fold_g: eps = (eps >> min(d_g,31)) + s_g     (exact; eps < 2^20)
//   inv = 65280 / eps ; out_k = inv >> min(M - x_k, 31)
//
// One wave per row; lanes 4a..4a+3 jointly hold group g = 16j+a per load j.
// nt loads: skip cache allocation for the read-once stream.
// plain stores: let L2 write-back batch the write stream (fills hit 6.6 TB/s
// through this path), smoothing HBM read/write turnaround.

typedef int iv4 __attribute__((ext_vector_type(4)));  // native vector: ok for nt builtins

constexpr int K = 2048;
constexpr int WAVES_PER_BLOCK = 4;

__global__ __launch_bounds__(256) void ita_softmax_kernel(
    const int* __restrict__ x, int* __restrict__ out, int nrows) {
  const int lane = threadIdx.x & 63;
  const int wave = threadIdx.x >> 6;
  const int row = blockIdx.x * WAVES_PER_BLOCK + wave;
  if (row >= nrows) return;  // wave-uniform (no barriers in this kernel)

  const int* xr = x + (size_t)row * K;
  iv4 xv[8];
  int pk[8];
  int A = -128;  // running max over all previous loads' groups (wave-uniform)

#pragma unroll
  for (int j = 0; j < 8; ++j) {
    xv[j] = __builtin_nontemporal_load(
        reinterpret_cast<const iv4*>(xr + 256 * j + 4 * lane));
    const iv4 v = xv[j];
    // group (cluster-of-4-lanes) max, replicated across the 4 lanes
    int gm = max(max(v.x, v.y), max(v.z, v.w));
    gm = max(gm, __shfl_xor(gm, 1));
    gm = max(gm, __shfl_xor(gm, 2));
    // inclusive prefix-max over the 16 clusters (values replicated x4, so a
    // lane-inclusive scan with strides 4,8,16,32 == cluster-inclusive scan)
    int cp = gm;
#pragma unroll
    for (int d = 4; d < 64; d <<= 1) {
      int t = __shfl_up(cp, d);
      if (lane >= d) cp = max(cp, t);
    }
    int ecp = __shfl_up(cp, 4);            // exclusive cluster prefix
    if (lane < 4) ecp = (int)0x80000000;   // cluster 0 has no predecessor
    const int P = max(A, cp);              // P_g (gmax after this group)
    const int Pp = max(A, ecp);            // P_{g-1} (gmax before this group)
    const int dd = min(P - Pp, 31);        // d_g clamped (eps < 2^20 so ok)
    // s_g partial over this lane's 4 elements (P >= element always)
    int sp = (256 >> min(P - v.x, 31)) + (256 >> min(P - v.y, 31)) +
             (256 >> min(P - v.z, 31)) + (256 >> min(P - v.w, 31));
    sp += __shfl_xor(sp, 1);
    sp += __shfl_xor(sp, 2);               // full group sum, <= 4096
    pk[j] = (dd << 16) | sp;
    A = max(A, __shfl(cp, 63));            // fold in this load's full max
  }
  const int M = A;  // row max

  // ---- exact serial fold over the 128 groups (readlane -> SALU chain) ----
  int eps = 0;
#pragma unroll
  for (int j = 0; j < 8; ++j) {
#pragma unroll
    for (int a = 0; a < 16; ++a) {
      const unsigned u = (unsigned)__builtin_amdgcn_readlane(pk[j], 4 * a);
      eps = (eps >> (u >> 16)) + (int)(u & 0xffffu);
    }
  }
  const int inv = 65280 / eps;  // eps >= 256 (row-max element, never shifted after)

  // ---- outputs straight from the live load registers, coalesced plain stores ----
  int* orow = out + (size_t)row * K;
#pragma unroll
  for (int j = 0; j < 8; ++j) {
    const iv4 v = xv[j];
    iv4 o;
    o.x = inv >> min(M - v.x, 31);  // inv <= 255, so shift >= 9 -> 0 == hw >=32 -> 0
    o.y = inv >> min(M - v.y, 31);
    o.z = inv >> min(M - v.z, 31);
    o.w = inv >> min(M - v.w, 31);
    *reinterpret_cast<iv4*>(orow + 256 * j + 4 * lane) = o;
  }
}

extern "C" void kernel_launch(void* const* d_in, const int* in_sizes, int n_in,
                              void* d_out, int out_size, void* d_ws, size_t ws_size,
                              hipStream_t stream) {
  const int* x = (const int*)d_in[0];
  int* out = (int*)d_out;
  const int nrows = in_sizes[0] / K;
  const int blocks = (nrows + WAVES_PER_BLOCK - 1) / WAVES_PER_BLOCK;
  ita_softmax_kernel<<<blocks, 256, 0, stream>>>(x, out, nrows);
}

// Round 7
// 185.425 us; speedup vs baseline: 1.0885x; 1.0885x over previous
//
#include <hip/hip_runtime.h>

// ITA integer softmax — register-resident; nontemporal loads AND stores
// (R3/R5/R6 matrix: plain/plain=207us, nt/plain=202us, nt/nt=190us — nt store
// avoids L2 write-allocate against the competing read stream; keep both nt).
// Loads are issued in their own loop before any shuffle work -> 8 outstanding
// global_load_dwordx4 per wave by construction.
//
// x: (2,16,2048,2048) int32 -> out uint8 values stored as int32.
// EPS_MAX = 1.0 exactly, so every float-round shift == integer difference.
// Exact reformulation per row (K=2048, 128 groups of 16):
//   P_g = prefix-max of group maxima (init -128), d_g = P_g - P_{g-1}
//   s_g = sum_k 256 >> min(P_g - x_k, 31)
//   eps = fold_g: eps = (eps >> min(d_g,31)) + s_g     (exact; eps < 2^20)
//   inv = 65280 / eps ; out_k = inv >> min(M - x_k, 31)
// One wave per row; lanes 4a..4a+3 jointly hold group g = 16j+a per load j.

typedef int iv4 __attribute__((ext_vector_type(4)));  // native vector: ok for nt builtins

constexpr int K = 2048;
constexpr int WAVES_PER_BLOCK = 4;

__global__ __launch_bounds__(256) void ita_softmax_kernel(
    const int* __restrict__ x, int* __restrict__ out, int nrows) {
  const int lane = threadIdx.x & 63;
  const int wave = threadIdx.x >> 6;
  const int row = blockIdx.x * WAVES_PER_BLOCK + wave;
  if (row >= nrows) return;  // wave-uniform (no barriers in this kernel)

  const int* xr = x + (size_t)row * K;
  iv4 xv[8];
  int pk[8];

  // ---- Phase A: issue all 8 nt loads (max MLP, no dependent work between) ----
#pragma unroll
  for (int j = 0; j < 8; ++j) {
    xv[j] = __builtin_nontemporal_load(
        reinterpret_cast<const iv4*>(xr + 256 * j + 4 * lane));
  }

  // ---- Phase B: per-load group stats as loads return ----
  int A = -128;  // running max over all previous loads' groups (wave-uniform)
#pragma unroll
  for (int j = 0; j < 8; ++j) {
    const iv4 v = xv[j];
    // group (cluster-of-4-lanes) max, replicated across the 4 lanes
    int gm = max(max(v.x, v.y), max(v.z, v.w));
    gm = max(gm, __shfl_xor(gm, 1));
    gm = max(gm, __shfl_xor(gm, 2));
    // inclusive prefix-max over the 16 clusters (values replicated x4, so a
    // lane-inclusive scan with strides 4,8,16,32 == cluster-inclusive scan)
    int cp = gm;
#pragma unroll
    for (int d = 4; d < 64; d <<= 1) {
      int t = __shfl_up(cp, d);
      if (lane >= d) cp = max(cp, t);
    }
    int ecp = __shfl_up(cp, 4);            // exclusive cluster prefix
    if (lane < 4) ecp = (int)0x80000000;   // cluster 0 has no predecessor
    const int P = max(A, cp);              // P_g (gmax after this group)
    const int Pp = max(A, ecp);            // P_{g-1} (gmax before this group)
    const int dd = min(P - Pp, 31);        // d_g clamped (eps < 2^20 so ok)
    // s_g partial over this lane's 4 elements (P >= element always)
    int sp = (256 >> min(P - v.x, 31)) + (256 >> min(P - v.y, 31)) +
             (256 >> min(P - v.z, 31)) + (256 >> min(P - v.w, 31));
    sp += __shfl_xor(sp, 1);
    sp += __shfl_xor(sp, 2);               // full group sum, <= 4096
    pk[j] = (dd << 16) | sp;
    A = max(A, __shfl(cp, 63));            // fold in this load's full max
  }
  const int M = A;  // row max

  // ---- exact serial fold over the 128 groups (readlane -> SALU chain) ----
  int eps = 0;
#pragma unroll
  for (int j = 0; j < 8; ++j) {
#pragma unroll
    for (int a = 0; a < 16; ++a) {
      const unsigned u = (unsigned)__builtin_amdgcn_readlane(pk[j], 4 * a);
      eps = (eps >> (u >> 16)) + (int)(u & 0xffffu);
    }
  }
  const int inv = 65280 / eps;  // eps >= 256 (row-max element, never shifted after)

  // ---- outputs straight from the live load registers, coalesced nt stores ----
  int* orow = out + (size_t)row * K;
#pragma unroll
  for (int j = 0; j < 8; ++j) {
    const iv4 v = xv[j];
    iv4 o;
    o.x = inv >> min(M - v.x, 31);  // inv <= 255, so shift >= 9 -> 0 == hw >=32 -> 0
    o.y = inv >> min(M - v.y, 31);
    o.z = inv >> min(M - v.z, 31);
    o.w = inv >> min(M - v.w, 31);
    __builtin_nontemporal_store(o, reinterpret_cast<iv4*>(orow + 256 * j + 4 * lane));
  }
}

extern "C" void kernel_launch(void* const* d_in, const int* in_sizes, int n_in,
                              void* d_out, int out_size, void* d_ws, size_t ws_size,
                              hipStream_t stream) {
  const int* x = (const int*)d_in[0];
  int* out = (int*)d_out;
  const int nrows = in_sizes[0] / K;
  const int blocks = (nrows + WAVES_PER_BLOCK - 1) / WAVES_PER_BLOCK;
  ita_softmax_kernel<<<blocks, 256, 0, stream>>>(x, out, nrows);
}